// Round 10
// baseline (133.619 us; speedup 1.0000x reference)
//
#include <hip/hip_runtime.h>

// HTMM: B_TREES=8, ARITY=4, DEPTH=8, C=8, M=100, NGEN=4
constexpr int OFFS1 = 8, OFFS2 = 40, OFFS3 = 168, OFFS4 = 680;
constexpr int OFFS5 = 2728, OFFS6 = 10920, OFFS7 = 43688, OFFS8 = 174760;

// lane mapping within a 32-lane group: r = g*8+s (g = gen, s = state)
// wq0..wq3 (F8 regs): wqJ[i] = P(child=s | parent=s^PX[i], pos J, gen g)  [lane (g,s)]
// emt_f[m*32+g*8+c] = P(obs m | state c, gen g)                 (fp32 LDS)
// etab_f[(m*4+j)*32+g*8+d] = sum_c P(c|d,j,g) em(m|c,g)         (fp32 LDS)
// R9 lesson: float wq[4][8] was DEMOTED TO SCRATCH (address-taken via array
// decay) -> 128 B/thread scratch stores (measured 16.7 MB WRITE) + hot-loop
// reloads. ext_vector_type values cannot be address-taken -> stay in VGPRs.

typedef float F8 __attribute__((ext_vector_type(8)));

#define AG_ST(p, v) __hip_atomic_store((p), (v), __ATOMIC_RELAXED, __HIP_MEMORY_SCOPE_AGENT)
#define AG_LD(p) __hip_atomic_load((p), __ATOMIC_RELAXED, __HIP_MEMORY_SCOPE_AGENT)

template <int CTRL>
static __device__ __forceinline__ float dppmov(float v) {
  return __int_as_float(__builtin_amdgcn_update_dpp(0, __float_as_int(v), CTRL, 0xF, 0xF, true));
}
// octet sum, all 8 lanes, pure VALU
static __device__ __forceinline__ float bfly8(float v) {
  v += dppmov<0xB1>(v);   // s^1
  v += dppmov<0x4E>(v);   // s^2
  v += dppmov<0x141>(v);  // 7-s (row_half_mirror)
  return v;
}
// PX[i] = {0,1,2,3,7,6,5,4}
static __device__ __forceinline__ F8 gather8(float v) {
  F8 o;
  float a1 = dppmov<0xB1>(v), a2 = dppmov<0x4E>(v), a3 = dppmov<0x1B>(v);
  o[0] = v;  o[1] = a1;  o[2] = a2;  o[3] = a3;
  o[4] = dppmov<0x141>(v);   // s^7
  o[5] = dppmov<0x141>(a1);  // s^6
  o[6] = dppmov<0x141>(a2);  // s^5
  o[7] = dppmov<0x141>(a3);  // s^4
  return o;
}
// top-down: child_prior[s] = sum_i w[i] * prior[s^PX[i]]
static __device__ __forceinline__ float mvc(F8 w, F8 o) {
  float acc = 0.f;
#pragma unroll
  for (int i = 0; i < 8; i++) acc += w[i] * o[i];
  return acc;
}
static __device__ __forceinline__ F8 wsel4(F8 w0, F8 w1, F8 w2, F8 w3, int j) {
  F8 a = (j & 1) ? w1 : w0;
  F8 bsel = (j & 1) ? w3 : w2;
  return (j & 2) ? bsel : a;
}
// upward: out[s] = sum_c P(child=c|parent=s,j) ratio[c] = sum_i DPP_{s^PX[i]}(w[i]*ratio)
// (xor perms self-inverse; cross-half mirror factored out of the 2nd quad-sum)
static __device__ __forceinline__ float mvup(F8 w, float ratio) {
  float inA = w[0] * ratio;
  inA += dppmov<0xB1>(w[1] * ratio);
  inA += dppmov<0x4E>(w[2] * ratio);
  inA += dppmov<0x1B>(w[3] * ratio);
  float inB = w[4] * ratio;              // s^7 = 141
  inB += dppmov<0xB1>(w[5] * ratio);     // s^6 = 141*B1
  inB += dppmov<0x4E>(w[6] * ratio);     // s^5 = 141*4E
  inB += dppmov<0x1B>(w[7] * ratio);     // s^4 = 141*1B
  return inA + dppmov<0x141>(inB);
}
static __device__ __forceinline__ float rcpf(float x) { return __builtin_amdgcn_rcpf(x); }

// LDS (floats, 17024 = 68.1 KB -> 2 blocks/CU, VGPR cap 256 w/ (256,2)):
// [0,1024)    wtd (phase0) -> rat5buf[16][32]+pri4buf[4][32] (phase1)
//             -> rat2buf[16][32]+rat1buf[4][32] (phase2)
// [1024,4224) emt_f (3200; reduce buf at the very end)
// [4224,17024) etab_f (12800, phase0/1) -> rat4_l 8192 f (phase2)
__global__ __launch_bounds__(256, 2) void k_all(const int* __restrict__ x,
                                                const float* __restrict__ A,
                                                const float* __restrict__ Bm,
                                                const float* __restrict__ Pi,
                                                float* __restrict__ RAT4,
                                                float* __restrict__ blocksum,
                                                unsigned* __restrict__ ctr,
                                                float* __restrict__ out) {
  __shared__ __align__(16) float smem[17024];
  __shared__ float llb[4];
  __shared__ int lastf;
  float* wtd_l = smem;
  float* rat5buf = smem;            // phase 1 (wtd dead)
  float* pri4buf = smem + 512;
  float* rat2buf = smem;            // phase 2
  float* rat1buf = smem + 512;
  float* emt_f = smem + 1024;       // 3200 floats
  float* etab_f = smem + 4224;      // 12800 floats
  float* rat4_l = smem + 4224;      // phase 2 alias (8192 floats)

  int t = threadIdx.x, r = t & 31, g = r >> 3, s = r & 7, grp = t >> 5;
  int b = blockIdx.x, tree = b >> 6;  // 64 blocks/tree

  // ---------------- phase 0: tables ----------------
  if (t < 128) {  // A softmax over child state; thread owns column (d,j,gg)
    int d = t >> 4, j = (t >> 2) & 3, gg = t & 3;
    float sum = 0.f;
    F8 v;
#pragma unroll
    for (int ss = 0; ss < 8; ss++) { v[ss] = __expf(A[((ss * 8 + d) * 4 + j) * 4 + gg]); sum += v[ss]; }
    float inv = rcpf(sum);
#pragma unroll
    for (int ss = 0; ss < 8; ss++) wtd_l[(j * 8 + d) * 32 + gg * 8 + ss] = v[ss] * inv;
  }
  if (t < 4) llb[t] = 0.f;
  {  // emission softmax over m: 32 rows (c,gg) x 8 octet partitions
    int row = t >> 3, part = t & 7, c = row >> 2, gg = row & 3;
    int m0 = part < 4 ? part * 13 : 52 + (part - 4) * 12;
    int mn = part < 4 ? 13 : 12;
    float sum = 0.f;
    for (int m = m0; m < m0 + mn; m++) sum += __expf(Bm[(c * 100 + m) * 4 + gg]);
    sum = bfly8(sum);
    float inv = rcpf(sum);
    for (int m = m0; m < m0 + mn; m++)
      emt_f[m * 32 + gg * 8 + c] = __expf(Bm[(c * 100 + m) * 4 + gg]) * inv;
  }
  float pit_r;  // per-lane root prior (no LDS)
  {
    float sum = 0.f, own = 0.f;
#pragma unroll
    for (int c = 0; c < 8; c++) {
      float e = __expf(Pi[c * 4 + g]);
      sum += e;
      if (c == s) own = e;
    }
    pit_r = own * rcpf(sum);
  }
  __syncthreads();
  F8 wq0, wq1, wq2, wq3;  // PX-permuted transition rows, pure registers
  {
    int sp0 = s, sp1 = s ^ 1, sp2 = s ^ 2, sp3 = s ^ 3;
    int sp4 = s ^ 7, sp5 = s ^ 6, sp6 = s ^ 5, sp7 = s ^ 4;
#define LOADWQ(W, J)                                                               \
  W[0] = wtd_l[((J) * 8 + sp0) * 32 + r]; W[1] = wtd_l[((J) * 8 + sp1) * 32 + r];  \
  W[2] = wtd_l[((J) * 8 + sp2) * 32 + r]; W[3] = wtd_l[((J) * 8 + sp3) * 32 + r];  \
  W[4] = wtd_l[((J) * 8 + sp4) * 32 + r]; W[5] = wtd_l[((J) * 8 + sp5) * 32 + r];  \
  W[6] = wtd_l[((J) * 8 + sp6) * 32 + r]; W[7] = wtd_l[((J) * 8 + sp7) * 32 + r];
    LOADWQ(wq0, 0) LOADWQ(wq1, 1) LOADWQ(wq2, 2) LOADWQ(wq3, 3)
#undef LOADWQ
  }
  {  // Etab: group handles j = grp&3, m-half = grp>>2 (upward matvec on em rows)
    int j = grp & 3, half = grp >> 2;
    F8 wsel = wsel4(wq0, wq1, wq2, wq3, j);
    for (int m = half * 50; m < half * 50 + 50; m++)
      etab_f[(m * 4 + j) * 32 + r] = mvup(wsel, emt_f[m * 32 + r]);
  }
  __syncthreads();  // wtd dead; rat5buf live

  // ---------------- phase 1: two level-5 subtrees per group ----------------
  float acc = 0.f;
#pragma unroll 1
  for (int round = 0; round < 2; round++) {
    int n5 = b * 16 + round * 8 + grp;
    float v = pit_r, pri4 = 0.f;
#pragma unroll
    for (int k = 1; k <= 5; k++) {
      F8 o = gather8(v);
      int j = (n5 >> (2 * (5 - k))) & 3;
      v = mvc(wsel4(wq0, wq1, wq2, wq3, j), o);
      if (k == 4) pri4 = v;
    }
    float v5 = v;
    F8 o5 = gather8(v5);

    const int4* x8v = (const int4*)(x + OFFS8 + n5 * 64);
    const int4* x7v = (const int4*)(x + OFFS7 + n5 * 16);
    int4 x6v = *(const int4*)(x + OFFS6 + n5 * 4);
    int x5s = x[OFFS5 + n5];
    const int* x6a = (const int*)&x6v;

    float l6r[4];
#pragma unroll
    for (int q6 = 0; q6 < 4; q6++) {
      int4 x7 = x7v[q6];
      const int* x7a = (const int*)&x7;
      float u6 = mvc(wsel4(wq0, wq1, wq2, wq3, q6), o5);
      F8 o6 = gather8(u6);
      float Ep[4][4];
#pragma unroll
      for (int q7 = 0; q7 < 4; q7++) {
        int4 xl = x8v[q6 * 4 + q7];
        const int* xla = (const int*)&xl;
#pragma unroll
        for (int j = 0; j < 4; j++) Ep[q7][j] = etab_f[(xla[j] * 4 + j) * 32 + r];
      }
      float rat7[4];
#pragma unroll
      for (int q7 = 0; q7 < 4; q7++) {
        float u7 = mvc(wsel4(wq0, wq1, wq2, wq3, q7), o6);
        float n0 = bfly8(u7 * Ep[q7][0]);
        float n1 = bfly8(u7 * Ep[q7][1]);
        float n2 = bfly8(u7 * Ep[q7][2]);
        float n3 = bfly8(u7 * Ep[q7][3]);
        float p01 = n0 * n1, p23 = n2 * n3;
        float prodL = (Ep[q7][0] * Ep[q7][1] * rcpf(p01)) * (Ep[q7][2] * Ep[q7][3] * rcpf(p23));
        float em = emt_f[x7a[q7] * 32 + r];
        float nu7 = bfly8(u7 * em * prodL);
        acc += __logf(p01 * p23) + __logf(nu7);
        rat7[q7] = em * prodL * rcpf(nu7);
      }
      float prod6 = mvup(wq0, rat7[0]) * mvup(wq1, rat7[1]) *
                    mvup(wq2, rat7[2]) * mvup(wq3, rat7[3]);
      float em6 = emt_f[x6a[q6] * 32 + r];
      float nu6 = bfly8(u6 * em6 * prod6);
      acc += __logf(nu6);
      l6r[q6] = em6 * prod6 * rcpf(nu6);
    }
    float prod5 = mvup(wq0, l6r[0]) * mvup(wq1, l6r[1]) *
                  mvup(wq2, l6r[2]) * mvup(wq3, l6r[3]);
    float em5 = emt_f[x5s * 32 + r];
    float nu5 = bfly8(v5 * em5 * prod5);
    acc += __logf(nu5);
    rat5buf[(round * 8 + grp) * 32 + r] = em5 * prod5 * rcpf(nu5);
    if ((grp & 3) == 0) pri4buf[(round * 2 + (grp >> 2)) * 32 + r] = pri4;
  }
  __syncthreads();

  // level-4: 4 nodes/block
  if (grp < 4) {
    int n4 = b * 4 + grp;
    float prod = mvup(wq0, rat5buf[(grp * 4 + 0) * 32 + r]) *
                 mvup(wq1, rat5buf[(grp * 4 + 1) * 32 + r]) *
                 mvup(wq2, rat5buf[(grp * 4 + 2) * 32 + r]) *
                 mvup(wq3, rat5buf[(grp * 4 + 3) * 32 + r]);
    float em = emt_f[x[OFFS4 + n4] * 32 + r];
    float nu = bfly8(pri4buf[grp * 32 + r] * em * prod);
    acc += __logf(nu);
    AG_ST(&RAT4[n4 * 32 + r], em * prod * rcpf(nu));
  }

  if (s == 0) atomicAdd(&llb[g], acc);
  __syncthreads();
  if (t < 4) AG_ST(&blocksum[b * 4 + t], llb[t]);
  asm volatile("s_waitcnt vmcnt(0)" ::: "memory");  // RAT4+blocksum at coherent point
  __syncthreads();
  if (t == 0) {
    unsigned old = __hip_atomic_fetch_add(&ctr[tree * 32], 1u, __ATOMIC_RELAXED,
                                          __HIP_MEMORY_SCOPE_AGENT);
    lastf = (old == 63u || old == 0xAAAAAAE9u) ? 1 : 0;  // zero-init or 0xAA poison
  }
  __syncthreads();
  if (!lastf) return;

  // ---------------- phase 2: last block of the tree, levels 3..0 ----------------
  {  // stage tree's RAT4 (8192 f) -> LDS, batched agent loads (etab region, dead)
    float tmp[8];
#pragma unroll
    for (int ib = 0; ib < 4; ib++) {
#pragma unroll
      for (int i = 0; i < 8; i++) tmp[i] = AG_LD(&RAT4[tree * 8192 + (ib * 8 + i) * 256 + t]);
#pragma unroll
      for (int i = 0; i < 8; i++) rat4_l[(ib * 8 + i) * 256 + t] = tmp[i];
    }
  }
  if (t < 4) llb[t] = 0.f;
  __syncthreads();

  float acc2 = 0.f;
#pragma unroll 1
  for (int ii = 0; ii < 2; ii++) {
    int l2 = ii * 8 + grp;
    int n2g = tree * 16 + l2;
    float v2 = pit_r;
#pragma unroll
    for (int k = 1; k <= 2; k++) {
      F8 o = gather8(v2);
      int j = (n2g >> (2 * (2 - k))) & 3;
      v2 = mvc(wsel4(wq0, wq1, wq2, wq3, j), o);
    }
    F8 o2 = gather8(v2);
    float rat3[4];
#pragma unroll
    for (int j3 = 0; j3 < 4; j3++) {
      int i3l = l2 * 4 + j3;
      float p3 = mvc(wsel4(wq0, wq1, wq2, wq3, j3), o2);
      float prod = mvup(wq0, rat4_l[(i3l * 4 + 0) * 32 + r]) *
                   mvup(wq1, rat4_l[(i3l * 4 + 1) * 32 + r]) *
                   mvup(wq2, rat4_l[(i3l * 4 + 2) * 32 + r]) *
                   mvup(wq3, rat4_l[(i3l * 4 + 3) * 32 + r]);
      float em = emt_f[x[OFFS3 + tree * 64 + i3l] * 32 + r];
      float nu = bfly8(p3 * em * prod);
      acc2 += __logf(nu);
      rat3[j3] = em * prod * rcpf(nu);
    }
    float prod2 = mvup(wq0, rat3[0]) * mvup(wq1, rat3[1]) *
                  mvup(wq2, rat3[2]) * mvup(wq3, rat3[3]);
    float em2 = emt_f[x[OFFS2 + n2g] * 32 + r];
    float nu2 = bfly8(v2 * em2 * prod2);
    acc2 += __logf(nu2);
    rat2buf[l2 * 32 + r] = em2 * prod2 * rcpf(nu2);
  }
  __syncthreads();
  if (grp < 4) {  // level 1
    float v1 = mvc(wsel4(wq0, wq1, wq2, wq3, grp), gather8(pit_r));
    float prod = mvup(wq0, rat2buf[(grp * 4 + 0) * 32 + r]) *
                 mvup(wq1, rat2buf[(grp * 4 + 1) * 32 + r]) *
                 mvup(wq2, rat2buf[(grp * 4 + 2) * 32 + r]) *
                 mvup(wq3, rat2buf[(grp * 4 + 3) * 32 + r]);
    float em = emt_f[x[OFFS1 + tree * 4 + grp] * 32 + r];
    float nu = bfly8(v1 * em * prod);
    acc2 += __logf(nu);
    rat1buf[grp * 32 + r] = em * prod * rcpf(nu);
  }
  __syncthreads();
  if (grp == 0) {  // root
    float prod = mvup(wq0, rat1buf[0 * 32 + r]) * mvup(wq1, rat1buf[1 * 32 + r]) *
                 mvup(wq2, rat1buf[2 * 32 + r]) * mvup(wq3, rat1buf[3 * 32 + r]);
    float em = emt_f[x[tree] * 32 + r];
    float nu = bfly8(pit_r * em * prod);
    acc2 += __logf(nu);
  }
  if (s == 0) atomicAdd(&llb[g], acc2);
  __syncthreads();
  // reduce 64 blocks x 4 gens (gen preserved mod 4); emt region dead now
  float* red = smem + 1024;
  red[t] = AG_LD(&blocksum[tree * 256 + t]);
  __syncthreads();
#pragma unroll
  for (int off = 128; off >= 4; off >>= 1) {
    if (t < off) red[t] += red[t + off];
    __syncthreads();
  }
  if (t < 4) out[tree * 4 + t] = red[t] + llb[t];
}

extern "C" void kernel_launch(void* const* d_in, const int* in_sizes, int n_in,
                              void* d_out, int out_size, void* d_ws, size_t ws_size,
                              hipStream_t stream) {
  const int* x = (const int*)d_in[0];
  const float* A = (const float*)d_in[1];
  const float* Bm = (const float*)d_in[2];
  const float* Pi = (const float*)d_in[3];
  float* ws = (float*)d_ws;
  unsigned* ctr = (unsigned*)d_ws;  // 8 trees x stride-32 uints (poison-based count)
  float* blocksum = ws + 256;       // 512 blocks x 4
  float* RAT4 = ws + 256 + 2048;    // 2048*32
  float* out = (float*)d_out;

  k_all<<<512, 256, 0, stream>>>(x, A, Bm, Pi, RAT4, blocksum, ctr, out);
}

// Round 11
// 109.680 us; speedup vs baseline: 1.2183x; 1.2183x over previous
//
#include <hip/hip_runtime.h>

// HTMM: B_TREES=8, ARITY=4, DEPTH=8, C=8, M=100, NGEN=4
constexpr int OFFS1 = 8, OFFS2 = 40, OFFS3 = 168, OFFS4 = 680;
constexpr int OFFS5 = 2728, OFFS6 = 10920, OFFS7 = 43688, OFFS8 = 174760;

// lane mapping within a 32-lane group: r = g*8+s (g = gen, s = state)
// wq[j][i] = P(child=s | parent=s^PX[i], pos j, gen g)   [PX = {0,1,2,3,7,6,5,4}]
//   -- serves BOTH top-down (MVC) and upward (MVUP) matvecs.
// emt_f[m*32+g*8+c] = P(obs m | state c, gen g)          (fp32 LDS)
// etab_f[(m*4+j)*32+g*8+d] = sum_c P(c|d,j,g) em(m|c,g)  (fp32 LDS)
// SPILL DISCIPLINE (R8-R10 lessons): allocator pins at 128 VGPR and spills
// address-taken arrays (R9: 16.7 MB scratch) and ext-vector tuples (R10:
// 137 MB). Here: live set ~100, arrays only literal-indexed via macros,
// all cross-lane values are scalars. __launch_bounds__(256) like R6 (no
// min-waves arg -- R3/R7/R8 showed those backfire).

#define AG_ST(p, v) __hip_atomic_store((p), (v), __ATOMIC_RELAXED, __HIP_MEMORY_SCOPE_AGENT)
#define AG_LD(p) __hip_atomic_load((p), __ATOMIC_RELAXED, __HIP_MEMORY_SCOPE_AGENT)

template <int CTRL>
static __device__ __forceinline__ float dppmov(float v) {
  return __int_as_float(__builtin_amdgcn_update_dpp(0, __float_as_int(v), CTRL, 0xF, 0xF, true));
}
// octet sum, all 8 lanes, pure VALU (xor1, xor2, octet-mirror)
static __device__ __forceinline__ float bfly8(float v) {
  v += dppmov<0xB1>(v);
  v += dppmov<0x4E>(v);
  v += dppmov<0x141>(v);
  return v;
}
static __device__ __forceinline__ float rcpf(float x) { return __builtin_amdgcn_rcpf(x); }

// upward: out[s] = sum_c P(c|s,j) rat[c] = sum_i DPP_i(w_i * rat); scalar args only
static __device__ __forceinline__ float mvup8(float w0, float w1, float w2, float w3,
                                              float w4, float w5, float w6, float w7,
                                              float rat) {
  float inA = w0 * rat;
  inA += dppmov<0xB1>(w1 * rat);
  inA += dppmov<0x4E>(w2 * rat);
  inA += dppmov<0x1B>(w3 * rat);
  float inB = w4 * rat;                // s^7 = mirror
  inB += dppmov<0xB1>(w5 * rat);       // s^6
  inB += dppmov<0x4E>(w6 * rat);       // s^5
  inB += dppmov<0x1B>(w7 * rat);       // s^4
  return inA + dppmov<0x141>(inB);
}
// J must be a literal (or unrolled-loop) constant: keeps wq in registers.
#define MVUP(J, rat) mvup8(wq[J][0], wq[J][1], wq[J][2], wq[J][3], \
                           wq[J][4], wq[J][5], wq[J][6], wq[J][7], (rat))
// all-gather: o##0..o##7 = v[s ^ PX[i]]
#define GATHER8(v, o)                 \
  float o##0 = (v);                   \
  float o##1 = dppmov<0xB1>(o##0);    \
  float o##2 = dppmov<0x4E>(o##0);    \
  float o##3 = dppmov<0x1B>(o##0);    \
  float o##4 = dppmov<0x141>(o##0);   \
  float o##5 = dppmov<0x141>(o##1);   \
  float o##6 = dppmov<0x141>(o##2);   \
  float o##7 = dppmov<0x141>(o##3);
// top-down with literal J: child[s] = sum_i wq[J][i] * o_i
#define MVC(J, o) (wq[J][0]*o##0 + wq[J][1]*o##1 + wq[J][2]*o##2 + wq[J][3]*o##3 + \
                   wq[J][4]*o##4 + wq[J][5]*o##5 + wq[J][6]*o##6 + wq[J][7]*o##7)
// top-down with RUNTIME j: weights straight from LDS (bank = r, conflict-free)
#define TDSTEP(jj, o) (wtd_l[(jj)*256 + a0]*o##0 + wtd_l[(jj)*256 + a1]*o##1 + \
                       wtd_l[(jj)*256 + a2]*o##2 + wtd_l[(jj)*256 + a3]*o##3 + \
                       wtd_l[(jj)*256 + a4]*o##4 + wtd_l[(jj)*256 + a5]*o##5 + \
                       wtd_l[(jj)*256 + a6]*o##6 + wtd_l[(jj)*256 + a7]*o##7)

// LDS (floats, 17664 = 70.7 KB -> 2 blocks/CU):
// [0,1024)     wtd_l (persistent; runtime-j path-walk weights)
// [1024,1664)  rat5buf[16][32]+pri4buf[4][32] (ph1) / rat2buf+rat1buf (ph2)
// [1664,4864)  emt_f 3200 (persistent; final reduce aliases it)
// [4864,17664) etab_f 12800 (ph0/1) / rat4_l 8192 (ph2)
__global__ __launch_bounds__(256) void k_all(const int* __restrict__ x,
                                             const float* __restrict__ A,
                                             const float* __restrict__ Bm,
                                             const float* __restrict__ Pi,
                                             float* __restrict__ RAT4,
                                             float* __restrict__ blocksum,
                                             unsigned* __restrict__ ctr,
                                             float* __restrict__ out) {
  __shared__ __align__(16) float smem[17664];
  __shared__ float llb[4];
  __shared__ int lastf;
  float* wtd_l = smem;
  float* rat5buf = smem + 1024;      // 512 (ph2: rat2buf)
  float* pri4buf = smem + 1536;      // 128 (ph2: rat1buf)
  float* emt_f = smem + 1664;        // 3200
  float* etab_f = smem + 4864;       // 12800
  float* rat4_l = smem + 4864;       // ph2 alias

  int t = threadIdx.x, r = t & 31, g = r >> 3, s = r & 7, grp = t >> 5;
  int b = blockIdx.x, tree = b >> 6;  // 64 blocks/tree

  // per-lane PX-permuted LDS offsets: a_i = (s^PX[i])*32 + r
  int a0 = s * 32 + r, a1 = (s ^ 1) * 32 + r, a2 = (s ^ 2) * 32 + r, a3 = (s ^ 3) * 32 + r;
  int a4 = (s ^ 7) * 32 + r, a5 = (s ^ 6) * 32 + r, a6 = (s ^ 5) * 32 + r, a7 = (s ^ 4) * 32 + r;

  // ---------------- phase 0: tables ----------------
  if (t < 128) {  // A softmax over child state; thread owns column (d,j,gg)
    int d = t >> 4, j = (t >> 2) & 3, gg = t & 3;
    float v0 = __expf(A[((0 * 8 + d) * 4 + j) * 4 + gg]), v1 = __expf(A[((1 * 8 + d) * 4 + j) * 4 + gg]);
    float v2 = __expf(A[((2 * 8 + d) * 4 + j) * 4 + gg]), v3 = __expf(A[((3 * 8 + d) * 4 + j) * 4 + gg]);
    float v4 = __expf(A[((4 * 8 + d) * 4 + j) * 4 + gg]), v5 = __expf(A[((5 * 8 + d) * 4 + j) * 4 + gg]);
    float v6 = __expf(A[((6 * 8 + d) * 4 + j) * 4 + gg]), v7 = __expf(A[((7 * 8 + d) * 4 + j) * 4 + gg]);
    float inv = rcpf(v0 + v1 + v2 + v3 + v4 + v5 + v6 + v7);
    float* wp = &wtd_l[(j * 8 + d) * 32 + gg * 8];
    wp[0] = v0 * inv; wp[1] = v1 * inv; wp[2] = v2 * inv; wp[3] = v3 * inv;
    wp[4] = v4 * inv; wp[5] = v5 * inv; wp[6] = v6 * inv; wp[7] = v7 * inv;
  }
  if (t < 4) llb[t] = 0.f;
  {  // emission softmax over m: 32 rows (c,gg) x 8 octet partitions
    int row = t >> 3, part = t & 7, c = row >> 2, gg = row & 3;
    int m0 = part < 4 ? part * 13 : 52 + (part - 4) * 12;
    int mn = part < 4 ? 13 : 12;
    float sum = 0.f;
    for (int m = m0; m < m0 + mn; m++) sum += __expf(Bm[(c * 100 + m) * 4 + gg]);
    sum = bfly8(sum);
    float inv = rcpf(sum);
    for (int m = m0; m < m0 + mn; m++)
      emt_f[m * 32 + gg * 8 + c] = __expf(Bm[(c * 100 + m) * 4 + gg]) * inv;
  }
  float pit_r;  // per-lane root prior
  {
    float sum = 0.f, own = 0.f;
#pragma unroll
    for (int c = 0; c < 8; c++) {
      float e = __expf(Pi[c * 4 + g]);
      sum += e;
      if (c == s) own = e;
    }
    pit_r = own * rcpf(sum);
  }
  __syncthreads();
  float wq[4][8];  // literal-indexed ONLY (macros); one table for both directions
#pragma unroll
  for (int j = 0; j < 4; j++) {
    wq[j][0] = wtd_l[j * 256 + a0]; wq[j][1] = wtd_l[j * 256 + a1];
    wq[j][2] = wtd_l[j * 256 + a2]; wq[j][3] = wtd_l[j * 256 + a3];
    wq[j][4] = wtd_l[j * 256 + a4]; wq[j][5] = wtd_l[j * 256 + a5];
    wq[j][6] = wtd_l[j * 256 + a6]; wq[j][7] = wtd_l[j * 256 + a7];
  }
  {  // Etab: group handles j = grp&3 (runtime -> LDS weights), m-half = grp>>2
    int je = grp & 3, half = grp >> 2;
    float we0 = wtd_l[je * 256 + a0], we1 = wtd_l[je * 256 + a1];
    float we2 = wtd_l[je * 256 + a2], we3 = wtd_l[je * 256 + a3];
    float we4 = wtd_l[je * 256 + a4], we5 = wtd_l[je * 256 + a5];
    float we6 = wtd_l[je * 256 + a6], we7 = wtd_l[je * 256 + a7];
    for (int m = half * 50; m < half * 50 + 50; m++)
      etab_f[(m * 4 + je) * 32 + r] = mvup8(we0, we1, we2, we3, we4, we5, we6, we7,
                                            emt_f[m * 32 + r]);
  }
  __syncthreads();

  // ---------------- phase 1: two level-5 subtrees per group ----------------
  float acc = 0.f;
#pragma unroll 1
  for (int round = 0; round < 2; round++) {
    int n5 = b * 16 + round * 8 + grp;
    float v = pit_r, pri4 = 0.f;
#pragma unroll
    for (int k = 1; k <= 5; k++) {
      int j = (n5 >> (2 * (5 - k))) & 3;
      GATHER8(v, o)
      v = TDSTEP(j, o);
      if (k == 4) pri4 = v;
    }
    float v5 = v;
    GATHER8(v5, p5)

    const int4* x8v = (const int4*)(x + OFFS8 + n5 * 64);
    const int4* x7v = (const int4*)(x + OFFS7 + n5 * 16);
    int4 x6v = *(const int4*)(x + OFFS6 + n5 * 4);
    int x5s = x[OFFS5 + n5];

    float l6r[4];
#pragma unroll
    for (int q6 = 0; q6 < 4; q6++) {
      int4 x7 = x7v[q6];
      float u6 = MVC(q6, p5);
      GATHER8(u6, p6)
      float Ep[4][4];
#pragma unroll
      for (int q7 = 0; q7 < 4; q7++) {
        int4 xl = x8v[q6 * 4 + q7];
        Ep[q7][0] = etab_f[(xl.x * 4 + 0) * 32 + r];
        Ep[q7][1] = etab_f[(xl.y * 4 + 1) * 32 + r];
        Ep[q7][2] = etab_f[(xl.z * 4 + 2) * 32 + r];
        Ep[q7][3] = etab_f[(xl.w * 4 + 3) * 32 + r];
      }
      float rat7[4];
#pragma unroll
      for (int q7 = 0; q7 < 4; q7++) {
        float u7 = MVC(q7, p6);
        float n0 = bfly8(u7 * Ep[q7][0]);
        float n1 = bfly8(u7 * Ep[q7][1]);
        float n2 = bfly8(u7 * Ep[q7][2]);
        float n3 = bfly8(u7 * Ep[q7][3]);
        float p01 = n0 * n1, p23 = n2 * n3;
        float prodL = (Ep[q7][0] * Ep[q7][1] * rcpf(p01)) * (Ep[q7][2] * Ep[q7][3] * rcpf(p23));
        int xm7 = (q7 == 0) ? x7.x : (q7 == 1) ? x7.y : (q7 == 2) ? x7.z : x7.w;
        float em = emt_f[xm7 * 32 + r];
        float nu7 = bfly8(u7 * em * prodL);
        acc += __logf(p01 * p23) + __logf(nu7);
        rat7[q7] = em * prodL * rcpf(nu7);
      }
      float prod6 = MVUP(0, rat7[0]) * MVUP(1, rat7[1]) * MVUP(2, rat7[2]) * MVUP(3, rat7[3]);
      int xm6 = (q6 == 0) ? x6v.x : (q6 == 1) ? x6v.y : (q6 == 2) ? x6v.z : x6v.w;
      float em6 = emt_f[xm6 * 32 + r];
      float nu6 = bfly8(u6 * em6 * prod6);
      acc += __logf(nu6);
      l6r[q6] = em6 * prod6 * rcpf(nu6);
    }
    float prod5 = MVUP(0, l6r[0]) * MVUP(1, l6r[1]) * MVUP(2, l6r[2]) * MVUP(3, l6r[3]);
    float em5 = emt_f[x5s * 32 + r];
    float nu5 = bfly8(v5 * em5 * prod5);
    acc += __logf(nu5);
    rat5buf[(round * 8 + grp) * 32 + r] = em5 * prod5 * rcpf(nu5);
    if ((grp & 3) == 0) pri4buf[(round * 2 + (grp >> 2)) * 32 + r] = pri4;
  }
  __syncthreads();

  // level-4: 4 nodes/block
  if (grp < 4) {
    int n4 = b * 4 + grp;
    float prod = MVUP(0, rat5buf[(grp * 4 + 0) * 32 + r]) *
                 MVUP(1, rat5buf[(grp * 4 + 1) * 32 + r]) *
                 MVUP(2, rat5buf[(grp * 4 + 2) * 32 + r]) *
                 MVUP(3, rat5buf[(grp * 4 + 3) * 32 + r]);
    float em = emt_f[x[OFFS4 + n4] * 32 + r];
    float nu = bfly8(pri4buf[grp * 32 + r] * em * prod);
    acc += __logf(nu);
    AG_ST(&RAT4[n4 * 32 + r], em * prod * rcpf(nu));
  }

  if (s == 0) atomicAdd(&llb[g], acc);
  __syncthreads();
  if (t < 4) AG_ST(&blocksum[b * 4 + t], llb[t]);
  asm volatile("s_waitcnt vmcnt(0)" ::: "memory");  // RAT4+blocksum at coherent point
  __syncthreads();
  if (t == 0) {
    unsigned old = __hip_atomic_fetch_add(&ctr[tree * 32], 1u, __ATOMIC_RELAXED,
                                          __HIP_MEMORY_SCOPE_AGENT);
    lastf = (old == 63u || old == 0xAAAAAAE9u) ? 1 : 0;  // zero-init or 0xAA poison
  }
  __syncthreads();
  if (!lastf) return;

  // ---------------- phase 2: last block of the tree, levels 3..0 ----------------
  {  // stage tree's RAT4 (8192 f) -> LDS (etab region, dead), batched agent loads
    float tmp[8];
#pragma unroll
    for (int ib = 0; ib < 4; ib++) {
#pragma unroll
      for (int i = 0; i < 8; i++) tmp[i] = AG_LD(&RAT4[tree * 8192 + (ib * 8 + i) * 256 + t]);
#pragma unroll
      for (int i = 0; i < 8; i++) rat4_l[(ib * 8 + i) * 256 + t] = tmp[i];
    }
  }
  if (t < 4) llb[t] = 0.f;
  __syncthreads();

  float* rat2buf = rat5buf;
  float* rat1buf = pri4buf;
  float acc2 = 0.f;
#pragma unroll 1
  for (int ii = 0; ii < 2; ii++) {
    int l2 = ii * 8 + grp;
    int n2g = tree * 16 + l2;
    int j1 = (l2 >> 2) & 3, j2 = l2 & 3;
    float v2;
    {
      GATHER8(pit_r, oa)
      float v1 = TDSTEP(j1, oa);
      GATHER8(v1, ob)
      v2 = TDSTEP(j2, ob);
    }
    GATHER8(v2, o2)
    float rat3[4];
#pragma unroll
    for (int j3 = 0; j3 < 4; j3++) {
      int i3l = l2 * 4 + j3;
      float p3 = MVC(j3, o2);
      float prod = MVUP(0, rat4_l[(i3l * 4 + 0) * 32 + r]) *
                   MVUP(1, rat4_l[(i3l * 4 + 1) * 32 + r]) *
                   MVUP(2, rat4_l[(i3l * 4 + 2) * 32 + r]) *
                   MVUP(3, rat4_l[(i3l * 4 + 3) * 32 + r]);
      float em = emt_f[x[OFFS3 + tree * 64 + i3l] * 32 + r];
      float nu = bfly8(p3 * em * prod);
      acc2 += __logf(nu);
      rat3[j3] = em * prod * rcpf(nu);
    }
    float prod2 = MVUP(0, rat3[0]) * MVUP(1, rat3[1]) * MVUP(2, rat3[2]) * MVUP(3, rat3[3]);
    float em2 = emt_f[x[OFFS2 + n2g] * 32 + r];
    float nu2 = bfly8(v2 * em2 * prod2);
    acc2 += __logf(nu2);
    rat2buf[l2 * 32 + r] = em2 * prod2 * rcpf(nu2);
  }
  __syncthreads();
  if (grp < 4) {  // level 1 (runtime j = grp -> LDS weights)
    GATHER8(pit_r, op)
    float v1 = TDSTEP(grp, op);
    float prod = MVUP(0, rat2buf[(grp * 4 + 0) * 32 + r]) *
                 MVUP(1, rat2buf[(grp * 4 + 1) * 32 + r]) *
                 MVUP(2, rat2buf[(grp * 4 + 2) * 32 + r]) *
                 MVUP(3, rat2buf[(grp * 4 + 3) * 32 + r]);
    float em = emt_f[x[OFFS1 + tree * 4 + grp] * 32 + r];
    float nu = bfly8(v1 * em * prod);
    acc2 += __logf(nu);
    rat1buf[grp * 32 + r] = em * prod * rcpf(nu);
  }
  __syncthreads();
  if (grp == 0) {  // root
    float prod = MVUP(0, rat1buf[0 * 32 + r]) * MVUP(1, rat1buf[1 * 32 + r]) *
                 MVUP(2, rat1buf[2 * 32 + r]) * MVUP(3, rat1buf[3 * 32 + r]);
    float em = emt_f[x[tree] * 32 + r];
    float nu = bfly8(pit_r * em * prod);
    acc2 += __logf(nu);
  }
  if (s == 0) atomicAdd(&llb[g], acc2);
  __syncthreads();
  // reduce 64 blocks x 4 gens (gen preserved mod 4); emt region dead now
  float* red = emt_f;
  red[t] = AG_LD(&blocksum[tree * 256 + t]);
  __syncthreads();
#pragma unroll
  for (int off = 128; off >= 4; off >>= 1) {
    if (t < off) red[t] += red[t + off];
    __syncthreads();
  }
  if (t < 4) out[tree * 4 + t] = red[t] + llb[t];
}

extern "C" void kernel_launch(void* const* d_in, const int* in_sizes, int n_in,
                              void* d_out, int out_size, void* d_ws, size_t ws_size,
                              hipStream_t stream) {
  const int* x = (const int*)d_in[0];
  const float* A = (const float*)d_in[1];
  const float* Bm = (const float*)d_in[2];
  const float* Pi = (const float*)d_in[3];
  float* ws = (float*)d_ws;
  unsigned* ctr = (unsigned*)d_ws;  // 8 trees x stride-32 uints (poison-based count)
  float* blocksum = ws + 256;       // 512 blocks x 4
  float* RAT4 = ws + 256 + 2048;    // 2048*32
  float* out = (float*)d_out;

  k_all<<<512, 256, 0, stream>>>(x, A, Bm, Pi, RAT4, blocksum, ctr, out);
}